// Round 3
// baseline (103.919 us; speedup 1.0000x reference)
//
#include <hip/hip_runtime.h>

#define BB 4096
#define TT 750
#define NS_STRIDE 768
#define NBLK 768           // 768 interior tiles; edge pairs folded into blocks 0..123
#define NRED 33            // k_B blocks (33*256 = 8448 = 11*768)

// ws float offsets (total < 1.2 MB)
// SYMMETRY: ns[t,k] = ns[t+k-6, 12-k], so k_A only computes k in [0,5] (k=6 is 0).
#define NSP_OFF    0                       // 12*384*64 transposed interior partials
#define EDGE_OFF   (4608 * 64)             // 124 edge partials (31 pairs x 4 chunks)
#define ENS_OFF    (EDGE_OFF + 128)        // 8448 = exp(-ns/2), layout [k][t] stride 768
#define FLAG_OFF   (ENS_OFF + 8448)        // 33 ints: per-k_B-block any(ens>0 && k!=6)
#define WACC_OFF   (FLAG_OFF + 64)         // 1 float: window accumulator (zeroed by k_B)
#define TICKET_OFF (WACC_OFF + 16)         // 1 uint: k_C ticket (zeroed by k_B), own line
#define RSLOT_OFF  (TICKET_OFF + 16)       // 768 per-block 0.1*sum(diff^2) partials

// ============ node 1: ns partials (k<6 only) + folded edge pairs + reg term ============
// Verbatim R0 baseline (plain coalesced stores — NO atomics; R2 showed 64-way-contended
// atomicAdd here costs ~10 us vs these stores).
__global__ __launch_bounds__(256, 4) void k_A(const float* __restrict__ a,
                                              const float* __restrict__ a2,
                                              float* __restrict__ ws) {
    float* ns_p   = ws + NSP_OFF;
    float* edge_c = ws + EDGE_OFF;
    float* rslots = ws + RSLOT_OFF;
    __shared__ float smem[2432];     // tile 32x76 = 2432; reduction reuses [0,1536)
    __shared__ float swred[4];
    __shared__ float swred2[4];
    const int b = blockIdx.x, tid = threadIdx.x;
    const int x = b % 12, y = b / 12;
    const int t0 = x * 64, i0 = y * 64;
    const int tl = tid & 63, ig = tid >> 6;

    float acc[6] = {0.f, 0.f, 0.f, 0.f, 0.f, 0.f};
    float racc = 0.f;                // reg-term accumulator

    for (int h = 0; h < 2; ++h) {
        for (int l = tid; l < 32 * 74; l += 256) {
            int r = l / 74, c = l - r * 74;
            int gc = t0 - 6 + c;
            float v = 0.f;
            if (gc >= 0 && gc < TT) v = a[(i0 + h * 32 + r) * TT + gc];
            smem[r * 76 + c] = v;
        }
        __syncthreads();
        // window loop, k in [0,5] only (q = t+k-6 in [t-6, t-1])
        if (x == 0) {
            // front tile: guard q >= 0  (q < TT impossible: q <= 57)
            for (int r = ig; r < 32; r += 4) {
                float xx = smem[r * 76 + tl + 6];
#pragma unroll
                for (int k = 0; k < 6; ++k) {
                    float d = xx - smem[r * 76 + tl + k];
                    if (tl + k >= 6) acc[k] += d * d;
                }
            }
        } else if (x == 11) {
            // back tile: t >= 704; q <= 748 < TT always; only t < TT guard
            const int t = t0 + tl;
            if (t < TT) {
                for (int r = ig; r < 32; r += 4) {
                    float xx = smem[r * 76 + tl + 6];
#pragma unroll
                    for (int k = 0; k < 6; ++k) {
                        float d = xx - smem[r * 76 + tl + k];
                        acc[k] += d * d;
                    }
                }
            }
        } else {
            // interior: no guards
            for (int r = ig; r < 32; r += 4) {
                float xx = smem[r * 76 + tl + 6];
#pragma unroll
                for (int k = 0; k < 6; ++k) {
                    float d = xx - smem[r * 76 + tl + k];
                    acc[k] += d * d;
                }
            }
        }
        // reg term: a[i,t] is a free LDS hit; a2 read coalesced
        {
            const int t = t0 + tl;
            if (t < TT) {
                for (int r = ig; r < 32; r += 4) {
                    float d = smem[r * 76 + tl + 6] - a2[(i0 + h * 32 + r) * TT + t];
                    racc += d * d;
                }
            }
        }
        __syncthreads();   // tile reads done before next-half overwrite / red aliasing
    }

    // reduction buffer aliases smem: red[ig][tl*6 + k], 4*384 = 1536 floats
#pragma unroll
    for (int k = 0; k < 6; ++k) smem[ig * 384 + tl * 6 + k] = acc[k];
    __syncthreads();

    // transposed store: ns_p[(x*384 + l)*64 + y]
    for (int l = tid; l < 384; l += 256) {
        float s = smem[l] + smem[384 + l] + smem[768 + l] + smem[1152 + l];
        ns_p[(size_t)(x * 384 + l) * 64 + y] = s;
    }

    // reg-term block reduction -> rslots[b] (already scaled by E_THETA)
    for (int off = 32; off > 0; off >>= 1) racc += __shfl_down(racc, off, 64);
    if (tl == 0) swred2[ig] = racc;
    __syncthreads();
    if (tid == 0)
        rslots[b] = 0.1f * (swred2[0] + swred2[1] + swred2[2] + swred2[3]);

    // folded edge work: blocks 0..123 -> pair q = b>>2, i-chunk ch = b&3 (verified R6-R10)
    if (b < 124) {
        const int q = b >> 2, ch = b & 3;
        int t = 0, k = 0;
        if (q < 21) {                       // front: t+k < 6, t-major
            int idx = q;
            for (int tt = 0; tt < 6; ++tt) {
                int c = 6 - tt;
                if (idx < c) { t = tt; k = idx; break; }
                idx -= c;
            }
        } else {                            // back: t+k >= 756
            int idx = q - 21;
            for (int tt = 746; tt < 750; ++tt) {
                int c = tt - 745;
                if (idx < c) { t = tt; k = (11 - c) + idx; break; }
                idx -= c;
            }
        }
        const int p = t + k;                // block-uniform
        float s = 0.f;
        int i = ch * 1024 + tid;
#pragma unroll
        for (int it = 0; it < 4; ++it, i += 256) {
            float xv = a[i * TT + t];
            float v = (p < 6) ? a[((6 * i + p) & (BB - 1)) * TT]
                              : a[((6 * i + (p - 755)) & (BB - 1)) * TT + (TT - 1)];
            float d = xv - v;
            s += d * d;
        }
        for (int off = 32; off > 0; off >>= 1) s += __shfl_down(s, off, 64);
        if (tl == 0) swred[ig] = s;
        __syncthreads();
        if (tid == 0)
            edge_c[q * 4 + ch] = swred[0] + swred[1] + swred[2] + swred[3];
    }
}

// ============ node 2: row-sum (mirror-aware) + edge, exp, per-block k!=6 flag ============
// Verbatim R0 baseline, plus: block 0 zero-inits wacc/ticket for k_C (stream-ordered,
// poison-proof, no extra memset dispatch).
__global__ __launch_bounds__(256) void k_B(const float* __restrict__ ws_ro,
                                           float* __restrict__ ws) {
    const float* ns_p   = ws_ro + NSP_OFF;
    const float* edge_c = ws_ro + EDGE_OFF;
    float* ens   = ws + ENS_OFF;
    int*   flags = (int*)(ws + FLAG_OFF);
    __shared__ int swf[4];
    const int b = blockIdx.x, tid = threadIdx.x;

    if (b == 0 && tid == 0) {
        ws[WACC_OFF] = 0.f;
        ((unsigned*)(ws + TICKET_OFF))[0] = 0u;
    }

    const int l = b * 256 + tid;
    const int k = l / NS_STRIDE;
    const int t = l - k * NS_STRIDE;
    float e = 0.f;
    if (t < TT) {
        if (k == 6) {
            e = 1.0f;
        } else {
            int row;
            if (k < 6) {
                row = (t >> 6) * 384 + (t & 63) * 6 + k;
            } else {
                int q = t + k - 6;          // <= 753 < 768, rows >= 750 are zero
                int kk = 12 - k;            // in [2,5]
                row = (q >> 6) * 384 + (q & 63) * 6 + kk;
            }
            const float4* pp4 = (const float4*)(ns_p + (size_t)row * 64);
            float s = 0.f;
#pragma unroll
            for (int j = 0; j < 16; ++j) {
                float4 v = pp4[j];
                s += v.x + v.y + v.z + v.w;
            }
            const int p = t + k;
            if (p < 6) {                    // only possible for k < 6
                int idx = t * 6 - t * (t - 1) / 2 + k;
                s += edge_c[idx * 4 + 0] + edge_c[idx * 4 + 1] +
                     edge_c[idx * 4 + 2] + edge_c[idx * 4 + 3];
            } else if (p >= 756) {          // only possible for k >= 7
                int idx = 21 + (t - 746) * (t - 745) / 2 + (k - (756 - t));
                s += edge_c[idx * 4 + 0] + edge_c[idx * 4 + 1] +
                     edge_c[idx * 4 + 2] + edge_c[idx * 4 + 3];
            }
            e = __expf(-0.5f * s);
        }
    }
    ens[l] = e;
    unsigned long long anyb = __ballot(e > 0.f && k != 6);
    if ((tid & 63) == 0) swf[tid >> 6] = (anyb != 0ull);
    __syncthreads();
    if (tid == 0) flags[b] = swf[0] | swf[1] | swf[2] | swf[3];
}

// ====== node 3: window term + last-block finalize (absorbs k_D via ticket) ======
__global__ __launch_bounds__(256, 4) void k_C(const float* __restrict__ a,
                                              const float* __restrict__ a2,
                                              float* __restrict__ ws,
                                              float* __restrict__ out) {
    const float* ens   = ws + ENS_OFF;
    const int*   flags = (const int*)(ws + FLAG_OFF);
    float* wacc = ws + WACC_OFF;
    unsigned* ticket = (unsigned*)(ws + TICKET_OFF);
    const float* rslots = ws + RSLOT_OFF;
    __shared__ float s_a4[268];
    __shared__ float s_a3[268];
    __shared__ float swred[4];
    __shared__ int   slast;
    const int b = blockIdx.x, tid = threadIdx.x;

    int flag = 0;
    for (int j = 0; j < NRED; ++j) flag |= flags[j];   // uniform, cross-kernel visible

    if (flag != 0) {
        // general path (verified R4-R10); partial -> wacc instead of slots
        const int x = b % 3;            // t-chunk
        const int y = b / 3;            // i-group
        const int t0 = x * 256;
        const int t = t0 + tid;
        float partial = 0.f;
        for (int ii = 0; ii < 16; ++ii) {
            const int i = y * 16 + ii;
            __syncthreads();
            for (int c = tid; c < 266; c += 256) {
                int p = t0 + c;
                float v4, v3;
                if (p < 6) {
                    int r = (6 * i + p) & (BB - 1);
                    v4 = a[r * TT];
                    v3 = a2[r * TT];
                } else if (p < 756) {
                    v4 = a[i * TT + p - 6];
                    v3 = a2[i * TT + p - 6];
                } else {
                    int r = (6 * i + (p - 755)) & (BB - 1);
                    v4 = a[r * TT + (TT - 1)];
                    v3 = a2[r * TT + (TT - 1)];
                }
                s_a4[c] = v4;
                s_a3[c] = v3;
            }
            __syncthreads();
            if (t < TT) {
                const float s2 = s_a3[tid + 6];
                float mw = -1e30f;
                float acc_d[11], acc_e[11];
#pragma unroll
                for (int k = 0; k < 11; ++k) {
                    float a4v = s_a4[tid + k];
                    float a3v = s_a3[tid + k];
                    int rr = (11 * i + k) & (BB - 1);
                    float tv = a[rr * TT + t];
                    mw = fmaxf(mw, tv - a4v);
                    acc_d[k] = fabsf(s2 - a3v);
                    acc_e[k] = ens[k * NS_STRIDE + t];
                }
                float g = mw * mw;                     // E_G
                float eg = __expf(-0.5f * g);          // SIGMA
                float acc = 0.f;
#pragma unroll
                for (int k = 0; k < 11; ++k) acc += fminf(acc_e[k], eg) * acc_d[k];
                partial += acc;
            }
        }
        for (int off = 32; off > 0; off >>= 1) partial += __shfl_down(partial, off, 64);
        if ((tid & 63) == 0) swred[tid >> 6] = partial;
        __syncthreads();
        if (tid == 0)
            atomicAdd(wacc, swred[0] + swred[1] + swred[2] + swred[3]);
    }

    // completion ticket; each block's wacc add (if any) ordered before its acq_rel RMW
    if (tid == 0) {
        unsigned my = __hip_atomic_fetch_add(ticket, 1u, __ATOMIC_ACQ_REL,
                                             __HIP_MEMORY_SCOPE_AGENT);
        slast = (my == NBLK - 1);
    }
    __syncthreads();

    if (slast) {
        // finalize: fast path bit-identical to old k_D (slots there were exact +0.0f,
        // and x + 0.0f == x for these non-negative sums)
        float v = rslots[tid] + rslots[tid + 256] + rslots[tid + 512];
        for (int off = 32; off > 0; off >>= 1) v += __shfl_down(v, off, 64);
        if ((tid & 63) == 0) swred[tid >> 6] = v;
        __syncthreads();
        if (tid == 0) {
            float tot = swred[0] + swred[1] + swred[2] + swred[3];
            float w = __hip_atomic_load(wacc, __ATOMIC_ACQUIRE, __HIP_MEMORY_SCOPE_AGENT);
            out[0] = (tot + w) * (1.0f / BB);   // E_ALPHA = 1; fast path: w == +0.0f
        }
    }
}

extern "C" void kernel_launch(void* const* d_in, const int* in_sizes, int n_in,
                              void* d_out, int out_size, void* d_ws, size_t ws_size,
                              hipStream_t stream) {
    const float* a  = (const float*)d_in[0];   // actioness
    const float* a2 = (const float*)d_in[1];   // actioness_2
    float* ws  = (float*)d_ws;
    float* out = (float*)d_out;

    k_A<<<NBLK, 256, 0, stream>>>(a, a2, ws);
    k_B<<<NRED, 256, 0, stream>>>(ws, ws);
    k_C<<<NBLK, 256, 0, stream>>>(a, a2, ws, out);
}

// Round 4
// 87.361 us; speedup vs baseline: 1.1895x; 1.1895x over previous
//
#include <hip/hip_runtime.h>

#define BB 4096
#define TT 750
#define NS_STRIDE 768
#define NBLK 768           // 768 interior tiles; edge pairs folded into blocks 0..123
#define NRED 33            // phase-2 blocks (33*256 = 8448 = 11*768)

// ws float offsets (total < 1.3 MB)
// SYMMETRY: ns[t,k] = ns[t+k-6, 12-k], so k_A only computes k in [0,5] (k=6 is 0).
// ns_p rows per x-tile: 64 t * 6 k = 384.
#define NSP_OFF   0                        // 12*384*64 transposed interior partials
#define EDGE_OFF  (4608 * 64)              // 124 edge partials (31 pairs x 4 chunks)
#define ENS_OFF   (EDGE_OFF + 128)         // 8448 = exp(-ns/2), layout [k][t] stride 768
#define SLOT_OFF  (ENS_OFF + 8448)         // 768 per-k_C-block window partial sums
#define FLAG_OFF  (SLOT_OFF + 768)         // 33 ints: per-k_B-block any(ens>0 && k!=6)
#define RSLOT_OFF (FLAG_OFF + 64)          // 768 per-k_A-block 0.1*sum(diff^2) partials

// NOTE (R1-R3 session evidence): do NOT replace these kernel boundaries with
// grid.sync (~100us each), device-scope tickets (+10-14us for 768 RMWs on one
// line), or contended atomicAdd accumulation (+5-10us). A kernel boundary
// (~1.5us) is the cheapest grid-wide barrier on gfx950's 8 non-coherent XCDs.

// ============ node 1: ns partials (k<6 only) + folded edge pairs + reg term ============
__global__ __launch_bounds__(256, 4) void k_A(const float* __restrict__ a,
                                              const float* __restrict__ a2,
                                              float* __restrict__ ws) {
    float* ns_p   = ws + NSP_OFF;
    float* edge_c = ws + EDGE_OFF;
    float* rslots = ws + RSLOT_OFF;
    __shared__ float smem[2432];     // tile 32x76 = 2432; reduction reuses [0,1536)
    __shared__ float swred[4];
    __shared__ float swred2[4];
    const int b = blockIdx.x, tid = threadIdx.x;
    const int x = b % 12, y = b / 12;
    const int t0 = x * 64, i0 = y * 64;
    const int tl = tid & 63, ig = tid >> 6;

    float acc[6] = {0.f, 0.f, 0.f, 0.f, 0.f, 0.f};
    float racc = 0.f;                // reg-term accumulator

    for (int h = 0; h < 2; ++h) {
        for (int l = tid; l < 32 * 74; l += 256) {
            int r = l / 74, c = l - r * 74;
            int gc = t0 - 6 + c;
            float v = 0.f;
            if (gc >= 0 && gc < TT) v = a[(i0 + h * 32 + r) * TT + gc];
            smem[r * 76 + c] = v;
        }
        __syncthreads();
        // window loop, k in [0,5] only (q = t+k-6 in [t-6, t-1])
        if (x == 0) {
            // front tile: guard q >= 0  (q < TT impossible: q <= 57)
            for (int r = ig; r < 32; r += 4) {
                float xx = smem[r * 76 + tl + 6];
#pragma unroll
                for (int k = 0; k < 6; ++k) {
                    float d = xx - smem[r * 76 + tl + k];
                    if (tl + k >= 6) acc[k] += d * d;
                }
            }
        } else if (x == 11) {
            // back tile: t >= 704; q <= 748 < TT always; only t < TT guard
            const int t = t0 + tl;
            if (t < TT) {
                for (int r = ig; r < 32; r += 4) {
                    float xx = smem[r * 76 + tl + 6];
#pragma unroll
                    for (int k = 0; k < 6; ++k) {
                        float d = xx - smem[r * 76 + tl + k];
                        acc[k] += d * d;
                    }
                }
            }
        } else {
            // interior: no guards
            for (int r = ig; r < 32; r += 4) {
                float xx = smem[r * 76 + tl + 6];
#pragma unroll
                for (int k = 0; k < 6; ++k) {
                    float d = xx - smem[r * 76 + tl + k];
                    acc[k] += d * d;
                }
            }
        }
        // reg term: a[i,t] is a free LDS hit; a2 read coalesced
        {
            const int t = t0 + tl;
            if (t < TT) {
                for (int r = ig; r < 32; r += 4) {
                    float d = smem[r * 76 + tl + 6] - a2[(i0 + h * 32 + r) * TT + t];
                    racc += d * d;
                }
            }
        }
        __syncthreads();   // tile reads done before next-half overwrite / red aliasing
    }

    // reduction buffer aliases smem: red[ig][tl*6 + k], 4*384 = 1536 floats
#pragma unroll
    for (int k = 0; k < 6; ++k) smem[ig * 384 + tl * 6 + k] = acc[k];
    __syncthreads();

    // transposed store: ns_p[(x*384 + l)*64 + y]
    for (int l = tid; l < 384; l += 256) {
        float s = smem[l] + smem[384 + l] + smem[768 + l] + smem[1152 + l];
        ns_p[(size_t)(x * 384 + l) * 64 + y] = s;
    }

    // reg-term block reduction -> rslots[b] (already scaled by E_THETA)
    for (int off = 32; off > 0; off >>= 1) racc += __shfl_down(racc, off, 64);
    if (tl == 0) swred2[ig] = racc;
    __syncthreads();
    if (tid == 0)
        rslots[b] = 0.1f * (swred2[0] + swred2[1] + swred2[2] + swred2[3]);

    // folded edge work: blocks 0..123 -> pair q = b>>2, i-chunk ch = b&3 (verified R6-R10)
    if (b < 124) {
        const int q = b >> 2, ch = b & 3;
        int t = 0, k = 0;
        if (q < 21) {                       // front: t+k < 6, t-major
            int idx = q;
            for (int tt = 0; tt < 6; ++tt) {
                int c = 6 - tt;
                if (idx < c) { t = tt; k = idx; break; }
                idx -= c;
            }
        } else {                            // back: t+k >= 756
            int idx = q - 21;
            for (int tt = 746; tt < 750; ++tt) {
                int c = tt - 745;
                if (idx < c) { t = tt; k = (11 - c) + idx; break; }
                idx -= c;
            }
        }
        const int p = t + k;                // block-uniform
        float s = 0.f;
        int i = ch * 1024 + tid;
#pragma unroll
        for (int it = 0; it < 4; ++it, i += 256) {
            float xv = a[i * TT + t];
            float v = (p < 6) ? a[((6 * i + p) & (BB - 1)) * TT]
                              : a[((6 * i + (p - 755)) & (BB - 1)) * TT + (TT - 1)];
            float d = xv - v;
            s += d * d;
        }
        for (int off = 32; off > 0; off >>= 1) s += __shfl_down(s, off, 64);
        if (tl == 0) swred[ig] = s;
        __syncthreads();
        if (tid == 0)
            edge_c[q * 4 + ch] = swred[0] + swred[1] + swred[2] + swred[3];
    }
}

// ============ node 2: row-sum (mirror-aware) + edge, exp, per-block k!=6 flag ============
// k == 6: ns = 0 structurally -> e = 1 (excluded from flag; its d2 is structurally 0).
// k <  6: direct row (t, k); possible front edge (p < 6).
// k >= 7: mirror row (q = t+k-6, 12-k); possible back edge (p >= 756, where the mirror
//         row lies in the guard-zeroed t>=750 region of tile 11 and edge_c completes it).
__global__ __launch_bounds__(256) void k_B(const float* __restrict__ ws_ro,
                                           float* __restrict__ ws) {
    const float* ns_p   = ws_ro + NSP_OFF;
    const float* edge_c = ws_ro + EDGE_OFF;
    float* ens   = ws + ENS_OFF;
    int*   flags = (int*)(ws + FLAG_OFF);
    __shared__ int swf[4];
    const int b = blockIdx.x, tid = threadIdx.x;
    const int l = b * 256 + tid;
    const int k = l / NS_STRIDE;
    const int t = l - k * NS_STRIDE;
    float e = 0.f;
    if (t < TT) {
        if (k == 6) {
            e = 1.0f;
        } else {
            int row;
            if (k < 6) {
                row = (t >> 6) * 384 + (t & 63) * 6 + k;
            } else {
                int q = t + k - 6;          // <= 753 < 768, rows >= 750 are zero
                int kk = 12 - k;            // in [2,5]
                row = (q >> 6) * 384 + (q & 63) * 6 + kk;
            }
            const float4* pp4 = (const float4*)(ns_p + (size_t)row * 64);
            float s = 0.f;
#pragma unroll
            for (int j = 0; j < 16; ++j) {
                float4 v = pp4[j];
                s += v.x + v.y + v.z + v.w;
            }
            const int p = t + k;
            if (p < 6) {                    // only possible for k < 6
                int idx = t * 6 - t * (t - 1) / 2 + k;
                s += edge_c[idx * 4 + 0] + edge_c[idx * 4 + 1] +
                     edge_c[idx * 4 + 2] + edge_c[idx * 4 + 3];
            } else if (p >= 756) {          // only possible for k >= 7
                int idx = 21 + (t - 746) * (t - 745) / 2 + (k - (756 - t));
                s += edge_c[idx * 4 + 0] + edge_c[idx * 4 + 1] +
                     edge_c[idx * 4 + 2] + edge_c[idx * 4 + 3];
            }
            e = __expf(-0.5f * s);
        }
    }
    ens[l] = e;
    unsigned long long anyb = __ballot(e > 0.f && k != 6);
    if ((tid & 63) == 0) swf[tid >> 6] = (anyb != 0ull);
    __syncthreads();
    if (tid == 0) flags[b] = swf[0] | swf[1] | swf[2] | swf[3];
}

// ============ node 3: window term only (reg term lives in k_A) ==========
__global__ __launch_bounds__(256, 4) void k_C(const float* __restrict__ a,
                                              const float* __restrict__ a2,
                                              float* __restrict__ ws) {
    const float* ens   = ws + ENS_OFF;
    const int*   flags = (const int*)(ws + FLAG_OFF);
    float* slots = ws + SLOT_OFF;
    const int b = blockIdx.x, tid = threadIdx.x;

    int flag = 0;
    for (int j = 0; j < NRED; ++j) flag |= flags[j];   // uniform, cross-kernel visible

    if (flag == 0) {
        // all ens (k!=6) zero; k=6 term structurally zero; reg term in k_A -> nothing here
        if (tid == 0) slots[b] = 0.f;
        return;
    }

    __shared__ float s_a4[268];
    __shared__ float s_a3[268];
    __shared__ float swred[4];
    const int x = b % 3;            // t-chunk
    const int y = b / 3;            // i-group
    const int t0 = x * 256;
    const int t = t0 + tid;

    float partial = 0.f;
    // general path (verified R4-R10, reg term removed); k=6 term multiplies d2==0
    for (int ii = 0; ii < 16; ++ii) {
        const int i = y * 16 + ii;
        __syncthreads();
        for (int c = tid; c < 266; c += 256) {
            int p = t0 + c;
            float v4, v3;
            if (p < 6) {
                int r = (6 * i + p) & (BB - 1);
                v4 = a[r * TT];
                v3 = a2[r * TT];
            } else if (p < 756) {
                v4 = a[i * TT + p - 6];
                v3 = a2[i * TT + p - 6];
            } else {
                int r = (6 * i + (p - 755)) & (BB - 1);
                v4 = a[r * TT + (TT - 1)];
                v3 = a2[r * TT + (TT - 1)];
            }
            s_a4[c] = v4;
            s_a3[c] = v3;
        }
        __syncthreads();
        if (t < TT) {
            const float s2 = s_a3[tid + 6];
            float mw = -1e30f;
            float acc_d[11], acc_e[11];
#pragma unroll
            for (int k = 0; k < 11; ++k) {
                float a4v = s_a4[tid + k];
                float a3v = s_a3[tid + k];
                int rr = (11 * i + k) & (BB - 1);
                float tv = a[rr * TT + t];
                mw = fmaxf(mw, tv - a4v);
                acc_d[k] = fabsf(s2 - a3v);
                acc_e[k] = ens[k * NS_STRIDE + t];
            }
            float g = mw * mw;                     // E_G
            float eg = __expf(-0.5f * g);          // SIGMA
            float acc = 0.f;
#pragma unroll
            for (int k = 0; k < 11; ++k) acc += fminf(acc_e[k], eg) * acc_d[k];
            partial += acc;
        }
    }

    for (int off = 32; off > 0; off >>= 1) partial += __shfl_down(partial, off, 64);
    if ((tid & 63) == 0) swred[tid >> 6] = partial;
    __syncthreads();
    if (tid == 0)
        slots[b] = swred[0] + swred[1] + swred[2] + swred[3];   // plain store, done
}

// ============ node 4: final reduce of window slots + reg slots ==========
__global__ __launch_bounds__(256) void k_D(const float* __restrict__ ws_ro,
                                           float* __restrict__ out) {
    const float* slots  = ws_ro + SLOT_OFF;
    const float* rslots = ws_ro + RSLOT_OFF;
    __shared__ float fred[4];
    const int tid = threadIdx.x;
    float v = slots[tid] + slots[tid + 256] + slots[tid + 512]
            + rslots[tid] + rslots[tid + 256] + rslots[tid + 512];
    for (int off = 32; off > 0; off >>= 1) v += __shfl_down(v, off, 64);
    if ((tid & 63) == 0) fred[tid >> 6] = v;
    __syncthreads();
    if (tid == 0)
        out[0] = (fred[0] + fred[1] + fred[2] + fred[3]) * (1.0f / BB);  // E_ALPHA
}

extern "C" void kernel_launch(void* const* d_in, const int* in_sizes, int n_in,
                              void* d_out, int out_size, void* d_ws, size_t ws_size,
                              hipStream_t stream) {
    const float* a  = (const float*)d_in[0];   // actioness
    const float* a2 = (const float*)d_in[1];   // actioness_2
    float* ws  = (float*)d_ws;
    float* out = (float*)d_out;

    k_A<<<NBLK, 256, 0, stream>>>(a, a2, ws);
    k_B<<<NRED, 256, 0, stream>>>(ws, ws);
    k_C<<<NBLK, 256, 0, stream>>>(a, a2, ws);
    k_D<<<1, 256, 0, stream>>>(ws, out);
}